// Round 16
// baseline (1097.966 us; speedup 1.0000x reference)
//
#include <hip/hip_runtime.h>
#include <math.h>

// Problem constants: B=32, L=4096, CH=1, H=256, NL=4, N2=32
// Residual stream Hbf is bf16 [b][h][l]. Chunked-linear S4D:
//   y = T_h u + W_h seed, S = V_h u, seeds via per-batch 16-chunk serial scan.
// R12 fused s4df; R14 coalesced prep; R16 gluln 1024-thr (16 waves x 16-ch strips:
// acc 128->32 regs/wave -> 4 waves/SIMD; position tile & weight amortization kept).
// ws layout (float units):
#define WS_WT   16777216   // wTb bf16 (NL,512,256): 262,144 f
#define WS_Y1   17039360   // y1 fp32: 8,192 f
#define WS_A256 17047552   // a256 fp32 [256h][32s][2]: 16,384 f
#define WS_V    17063936   // V bf16 [256h][64][256]: 2,097,152 f
#define WS_ABUF 19161088   // A=[T|W] bf16 [256h][256][320]: 10,485,760 f
#define WS_S    29646848   // (slot retained) then Gb
// high-water nb=32: 29,646,848 + 32*655,360 = 50,618,368 f = 202.5 MB

typedef unsigned short ushort_t;
struct __attribute__((aligned(8))) us4 { ushort_t x, y, z, w; };
typedef short bf16x8 __attribute__((ext_vector_type(8)));
typedef float f32x4  __attribute__((ext_vector_type(4)));

__device__ __forceinline__ float bf2f(ushort_t u) {
    union { unsigned int i; float f; } c; c.i = ((unsigned int)u) << 16; return c.f;
}
__device__ __forceinline__ ushort_t f2bf(float f) {
    union { float f; unsigned int i; } c; c.f = f;
    unsigned int x = c.i;
    unsigned int r = (x + 0x7FFF + ((x >> 16) & 1)) >> 16;   // RNE
    return (ushort_t)r;
}
// gelu via tanh-form sigmoid: max |err| vs exact erf-gelu ~7e-4, overflow-safe.
__device__ __forceinline__ float fast_gelu(float v) {
    float y = 1.5957691216057308f * (v + 0.044715f * v * v * v); // 2*sqrt(2/pi)
    return v / (1.f + __expf(-y));
}

// ---------------- encoder: bf16 h[b][h][l] ----------------
__global__ __launch_bounds__(256) void enc_kernel(const float* __restrict__ x,
    const float* __restrict__ ew, const float* __restrict__ eb, ushort_t* __restrict__ Hb)
{
    int i = blockIdx.x * 256 + threadIdx.x;      // 8-us units, 4,194,304 total
    int l8 = i & 511;
    int h  = (i >> 9) & 255;
    int b  = i >> 17;
    const float* xp = x + ((size_t)b << 12) + (l8 << 3);
    float4 a0 = ((const float4*)xp)[0];
    float4 a1 = ((const float4*)xp)[1];
    float w = ew[h], bb = eb[h];
    us4 o0, o1;
    o0.x = f2bf(fmaf(a0.x, w, bb)); o0.y = f2bf(fmaf(a0.y, w, bb));
    o0.z = f2bf(fmaf(a0.z, w, bb)); o0.w = f2bf(fmaf(a0.w, w, bb));
    o1.x = f2bf(fmaf(a1.x, w, bb)); o1.y = f2bf(fmaf(a1.y, w, bb));
    o1.z = f2bf(fmaf(a1.z, w, bb)); o1.w = f2bf(fmaf(a1.w, w, bb));
    us4* op = (us4*)(Hb + ((size_t)i << 3));
    op[0] = o0; op[1] = o1;
}

// ---------------- weight cast ----------------
__global__ __launch_bounds__(256) void wtb_kernel(const float* __restrict__ gw, ushort_t* __restrict__ wTb)
{
    int i = blockIdx.x * 256 + threadIdx.x;      // 524,288
    wTb[i] = f2bf(gw[i]);
}

// ---------------- prep: build A=[T|W], V, a256; coalesced Abuf writeout --------------
__global__ __launch_bounds__(256) void prep_kernel(
    const float* __restrict__ log_dt, const float* __restrict__ lAr,
    const float* __restrict__ Aim_, const float* __restrict__ Cre,
    const float* __restrict__ Cim, ushort_t* __restrict__ Abuf,
    ushort_t* __restrict__ Vg, float* __restrict__ a256tab, int li)
{
    __shared__ float s_ar[32], s_ai[32], s_ckr[32], s_cki[32];
    __shared__ float powr[8][32], powi[8][32];
    __shared__ ushort_t kb[256];
    __shared__ ushort_t Vt[256][66];
    __shared__ ushort_t Wt[256][66];
    int t = threadIdx.x;
    int h = blockIdx.x;
    int pb = (li * 256 + h) * 32;

    if (t < 32) {
        int s = t;
        float dt = expf(log_dt[li * 256 + h]);
        float Are = -expf(lAr[pb + s]);
        float Ai  = Aim_[pb + s];
        float e = expf(Are * dt);
        float ar = e * cosf(Ai * dt), ai = e * sinf(Ai * dt);
        float inv = 1.f / (Are * Are + Ai * Ai);
        float numr = ar - 1.f, numi = ai;
        float tr = (numr * Are + numi * Ai) * inv;
        float ti = (numi * Are - numr * Ai) * inv;
        float cr = Cre[pb + s], ci = Cim[pb + s];
        s_ar[s] = ar; s_ai[s] = ai;
        s_ckr[s] = 2.f * (cr * tr - ci * ti);
        s_cki[s] = 2.f * (cr * ti + ci * tr);
        float xr = ar, xi = ai;
        for (int k = 0; k < 8; k++) {
            powr[k][s] = xr; powi[k][s] = xi;
            float nr = xr * xr - xi * xi;
            float ni = 2.f * xr * xi;
            xr = nr; xi = ni;
        }
        a256tab[h * 64 + s * 2] = xr;
        a256tab[h * 64 + s * 2 + 1] = xi;
    }
    __syncthreads();

    int d = t;
    float adr[32], adi[32];
    #pragma unroll
    for (int s = 0; s < 32; s++) { adr[s] = 1.f; adi[s] = 0.f; }
    #pragma unroll
    for (int bit = 0; bit < 8; bit++) {
        if (d & (1 << bit)) {
            #pragma unroll
            for (int s = 0; s < 32; s++) {
                float pr_ = powr[bit][s], pi_ = powi[bit][s];
                float nr = adr[s] * pr_ - adi[s] * pi_;
                float ni = adr[s] * pi_ + adi[s] * pr_;
                adr[s] = nr; adi[s] = ni;
            }
        }
    }
    float kd = 0.f;
    #pragma unroll
    for (int s = 0; s < 32; s++) kd += s_ckr[s] * adr[s] - s_cki[s] * adi[s];
    kb[d] = f2bf(kd);
    #pragma unroll
    for (int s = 0; s < 32; s++) {                // W row d -> Wt (LDS)
        float wr = adr[s] * s_ar[s] - adi[s] * s_ai[s];
        float wi = adr[s] * s_ai[s] + adi[s] * s_ar[s];
        float v0 = s_ckr[s] * wr - s_cki[s] * wi;
        float v1 = -(s_ckr[s] * wi + s_cki[s] * wr);
        *(unsigned int*)&Wt[d][2 * s] =
            (unsigned int)f2bf(v0) | ((unsigned int)f2bf(v1) << 16);
    }
    {
        int e = 255 - d;
        float evr[32], evi[32];
        #pragma unroll
        for (int s = 0; s < 32; s++) { evr[s] = 1.f; evi[s] = 0.f; }
        #pragma unroll
        for (int bit = 0; bit < 8; bit++) {
            if (e & (1 << bit)) {
                #pragma unroll
                for (int s = 0; s < 32; s++) {
                    float pr_ = powr[bit][s], pi_ = powi[bit][s];
                    float nr = evr[s] * pr_ - evi[s] * pi_;
                    float ni = evr[s] * pi_ + evi[s] * pr_;
                    evr[s] = nr; evi[s] = ni;
                }
            }
        }
        #pragma unroll
        for (int s = 0; s < 32; s++) {
            Vt[d][2*s]   = f2bf(evr[s]);
            Vt[d][2*s+1] = f2bf(evi[s]);
        }
    }
    __syncthreads();

    // coalesced [T|W] writeout: thread t stores us4 f = i*256+t
    {
        ushort_t* Ab = Abuf + (size_t)h * 81920;
        #pragma unroll 4
        for (int i = 0; i < 80; i++) {
            int f = i * 256 + t;                  // 0..20479
            int row = f / 80;
            int cq = f - row * 80;
            int col = cq * 4;
            us4 v;
            if (col < 256) {
                int idx = row - col;
                v.x = (idx >= 0) ? kb[idx]     : (ushort_t)0;
                v.y = (idx >= 1) ? kb[idx - 1] : (ushort_t)0;
                v.z = (idx >= 2) ? kb[idx - 2] : (ushort_t)0;
                v.w = (idx >= 3) ? kb[idx - 3] : (ushort_t)0;
            } else {
                int wc = col - 256;
                v.x = Wt[row][wc]; v.y = Wt[row][wc + 1];
                v.z = Wt[row][wc + 2]; v.w = Wt[row][wc + 3];
            }
            *(us4*)(Ab + (size_t)f * 4) = v;
        }
    }
    // V out
    {
        int m = t >> 2, jq = t & 3;
        ushort_t* vrow = Vg + (size_t)h * 16384 + (size_t)m * 256 + jq * 64;
        for (int j4 = 0; j4 < 16; j4++) {
            int j = jq * 64 + j4 * 4;
            us4 v;
            v.x = Vt[j][m]; v.y = Vt[j+1][m]; v.z = Vt[j+2][m]; v.w = Vt[j+3][m];
            *(us4*)(vrow + j4 * 4) = v;
        }
    }
}

// ---------------- fused S4D: V-GEMM -> LDS scan -> [T|W]-GEMM + gelu -> G ------------
__global__ __launch_bounds__(256, 2) void s4df_kernel(
    const ushort_t* __restrict__ U, const ushort_t* __restrict__ Abuf,
    const ushort_t* __restrict__ Vg, const float* __restrict__ a256tab,
    const float* __restrict__ Dp, ushort_t* __restrict__ G, int li, int b0)
{
    __shared__ ushort_t yt[64 * 320];             // 40 KiB, chunk c' = c ^ (row&7)
    __shared__ ushort_t sS[64 * 66];              // 8.25 KiB: S[m][n]
    int t = threadIdx.x;
    int h = blockIdx.x;
    int tile = blockIdx.y;
    int nl = t & 63, kq = t >> 6;
    int n = tile * 64 + nl;
    int sw = nl & 7;
    const ushort_t* ub = U + (size_t)(b0 + (n >> 4)) * 1048576 + (size_t)h * 4096 + (n & 15) * 256;
    #pragma unroll
    for (int i = 0; i < 8; i++) {
        int c = kq * 8 + i;
        *(uint4*)(&yt[nl * 320 + ((c ^ sw) << 3)]) = *(const uint4*)(ub + c * 8);
    }
    __syncthreads();

    int lane = t & 63, w = t >> 6;
    int ln15 = lane & 15, quad = lane >> 4;
    int rsw = ln15 & 7;

    // --- V-GEMM: S = V_h . u (va loads double-buffered) ---
    {
        const ushort_t* va = Vg + (size_t)h * 16384 + (size_t)(w * 16 + ln15) * 256;
        f32x4 acc[4] = {};
        bf16x8 vab[2];
        vab[0] = *(const bf16x8*)(va + quad * 8);
        #pragma unroll
        for (int ks = 0; ks < 8; ks++) {
            int cur = ks & 1;
            if (ks < 7) vab[cur ^ 1] = *(const bf16x8*)(va + (ks + 1) * 32 + quad * 8);
            int c = ks * 4 + quad;
            #pragma unroll
            for (int nt = 0; nt < 4; nt++) {
                bf16x8 bf_ = *(const bf16x8*)(&yt[(nt * 16 + ln15) * 320 + ((c ^ rsw) << 3)]);
                acc[nt] = __builtin_amdgcn_mfma_f32_16x16x32_bf16(vab[cur], bf_, acc[nt], 0, 0, 0);
            }
        }
        #pragma unroll
        for (int nt = 0; nt < 4; nt++) {
            int m = w * 16 + quad * 4;
            int nn = nt * 16 + ln15;
            sS[(m    ) * 66 + nn] = f2bf(acc[nt][0]);
            sS[(m + 1) * 66 + nn] = f2bf(acc[nt][1]);
            sS[(m + 2) * 66 + nn] = f2bf(acc[nt][2]);
            sS[(m + 3) * 66 + nn] = f2bf(acc[nt][3]);
        }
    }
    __syncthreads();

    // --- per-batch serial scan (4 b x 32 states), seeds -> yt cols 256..319 ---
    if (t < 128) {
        int bq = t >> 5, s = t & 31;
        float m2r = a256tab[h * 64 + s * 2], m2i = a256tab[h * 64 + s * 2 + 1];
        int col = 256 + 2 * s;
        int cc = col >> 3, off = col & 7;
        float sr = 0.f, si = 0.f;
        for (int c = 0; c < 16; c++) {
            int nn = bq * 16 + c;
            float Sr = bf2f(sS[(2 * s) * 66 + nn]);
            float Si = bf2f(sS[(2 * s + 1) * 66 + nn]);
            int addr = nn * 320 + ((cc ^ (nn & 7)) << 3) + off;
            yt[addr] = f2bf(sr);
            yt[addr + 1] = f2bf(si);
            float nsr = m2r * sr - m2i * si + Sr;
            float nsi = m2r * si + m2i * sr + Si;
            sr = nsr; si = nsi;
        }
    }
    __syncthreads();

    // --- main GEMM: y = [T|W].[u;seed], + D*u, gelu -> G (af double-buffered) ---
    const ushort_t* Ah = Abuf + (size_t)h * 81920 + (size_t)(w * 64 + ln15) * 320 + quad * 8;
    f32x4 acc[4][4] = {};
    bf16x8 afb[2][4];
    #pragma unroll
    for (int mt = 0; mt < 4; mt++)
        afb[0][mt] = *(const bf16x8*)(Ah + (size_t)(mt * 16) * 320);
    #pragma unroll
    for (int ks = 0; ks < 10; ks++) {
        int cur = ks & 1;
        if (ks < 9) {
            #pragma unroll
            for (int mt = 0; mt < 4; mt++)
                afb[cur ^ 1][mt] = *(const bf16x8*)(Ah + (size_t)(mt * 16) * 320 + (ks + 1) * 32);
        }
        int c = ks * 4 + quad;
        #pragma unroll
        for (int nt = 0; nt < 4; nt++) {
            bf16x8 bf_ = *(const bf16x8*)(&yt[(nt * 16 + ln15) * 320 + ((c ^ rsw) << 3)]);
            #pragma unroll
            for (int mt = 0; mt < 4; mt++)
                acc[mt][nt] = __builtin_amdgcn_mfma_f32_16x16x32_bf16(afb[cur][mt], bf_, acc[mt][nt], 0, 0, 0);
        }
    }
    float Dh = Dp[li * 256 + h];
    #pragma unroll
    for (int mt = 0; mt < 4; mt++) {
        #pragma unroll
        for (int nt = 0; nt < 4; nt++) {
            int nn = tile * 64 + nt * 16 + ln15;
            int lb = w * 64 + mt * 16 + quad * 4;
            int c = lb >> 3, co = lb & 7;
            us4 uv = *(const us4*)(&yt[(nt * 16 + ln15) * 320 + ((c ^ rsw) << 3) + co]);
            float uu[4] = {bf2f(uv.x), bf2f(uv.y), bf2f(uv.z), bf2f(uv.w)};
            us4 o;
            ushort_t* op = &o.x;
            #pragma unroll
            for (int rr = 0; rr < 4; rr++) {
                float v = acc[mt][nt][rr] + Dh * uu[rr];
                op[rr] = f2bf(fast_gelu(v));
            }
            ushort_t* gp = G + ((size_t)(nn >> 4) * 256 + h) * 4096 + (nn & 15) * 256 + lb;
            *(us4*)gp = o;
        }
    }
}

// ---------------- GLU + residual + LayerNorm fused; 1024-thr, 16-ch strips ----------
// R16: 16 waves x (16 a-ch + 16 g-ch) over the SAME 64-position tile. Per-wave acc
// 32 regs (was 128) -> ~110 total -> 4 waves/SIMD (was 2). Weight bytes/block and
// position tile unchanged (R10's amortization loss and R13's spill both excluded).
#define LDK 268
__global__ __launch_bounds__(1024, 4) void gluln_kernel(
    const ushort_t* __restrict__ G, const ushort_t* __restrict__ wTb,
    const float* __restrict__ glu_b, const float* __restrict__ ln_g,
    const float* __restrict__ ln_b, ushort_t* __restrict__ Hb, int li, int b0)
{
    __shared__ ushort_t yt[64 * LDK];             // 34,304 B
    __shared__ float sred[16][64], sqred[16][64]; // 8 KiB
    __shared__ float mup[64], rstd[64];
    int t = threadIdx.x;                          // 0..1023
    int pf = blockIdx.x * 64;
    int bloc = pf >> 12;
    int l0 = pf & 4095;
    int b = b0 + bloc;

    const ushort_t* gb = G + (size_t)bloc * 1048576 + l0;
    unsigned int* dst = (unsigned int*)&yt[0];
    {
        int hp = t >> 3;                          // 0..127 (h pair)
        int pg = t & 7;                           // 0..7 (8-pos group)
        int h0 = hp * 2;
        uint4 va = *(const uint4*)(gb + (size_t)h0 * 4096 + pg * 8);
        uint4 vb = *(const uint4*)(gb + (size_t)(h0 + 1) * 4096 + pg * 8);
        const ushort_t* ra = (const ushort_t*)&va;
        const ushort_t* rb = (const ushort_t*)&vb;
        #pragma unroll
        for (int j = 0; j < 8; j++) {
            unsigned int v = (unsigned int)ra[j] | ((unsigned int)rb[j] << 16);
            dst[(pg * 8 + j) * (LDK / 2) + hp] = v;
        }
    }
    __syncthreads();

    int lane = t & 63, w = t >> 6;                // w in 0..15
    int ln15 = lane & 15, quad = lane >> 4;
    int o = w * 16 + ln15;                        // this lane's a-channel
    const ushort_t* wA = wTb + li * 131072;
    const ushort_t* wap = wA + (size_t)o * 256;
    const ushort_t* wgp = wA + (size_t)(o + 256) * 256;

    f32x4 accA[4] = {};                           // row=quad*4+r (p), col=ln15 (o)
    f32x4 accG[4] = {};

    for (int ks = 0; ks < 8; ks++) {
        int kk = ks * 32 + quad * 8;
        bf16x8 af = *(const bf16x8*)(wap + kk);
        bf16x8 gf = *(const bf16x8*)(wgp + kk);
        #pragma unroll
        for (int nt = 0; nt < 4; nt++) {
            const us4* yp = (const us4*)&yt[(nt * 16 + ln15) * LDK + kk];
            us4 lo = yp[0], hi = yp[1];
            bf16x8 v;
            v[0] = (short)lo.x; v[1] = (short)lo.y; v[2] = (short)lo.z; v[3] = (short)lo.w;
            v[4] = (short)hi.x; v[5] = (short)hi.y; v[6] = (short)hi.z; v[7] = (short)hi.w;
            accA[nt] = __builtin_amdgcn_mfma_f32_16x16x32_bf16(v, af, accA[nt], 0, 0, 0);
            accG[nt] = __builtin_amdgcn_mfma_f32_16x16x32_bf16(v, gf, accG[nt], 0, 0, 0);
        }
    }

    // prefetch H-old: us4 at (o, p = nt*16+quad*4..+3)
    ushort_t* hb_ = Hb + (size_t)b * 1048576;
    const ushort_t* hrow = hb_ + (size_t)o * 4096 + l0 + quad * 4;
    us4 hold[4];
    #pragma unroll
    for (int nt = 0; nt < 4; nt++) hold[nt] = *(const us4*)(hrow + nt * 16);

    float bav = glu_b[li * 512 + o];
    float bgv = glu_b[li * 512 + 256 + o];

    float psl[4][4] = {}, pql[4][4] = {};
    #pragma unroll
    for (int nt = 0; nt < 4; nt++) {
        const ushort_t* hp4 = &hold[nt].x;
        #pragma unroll
        for (int r = 0; r < 4; r++) {
            float a = accA[nt][r] + bav;
            float g = accG[nt][r] + bgv;
            float z = a / (1.f + __expf(-g));
            float hn = z + bf2f(hp4[r]);
            accA[nt][r] = hn;
            psl[nt][r] += hn; pql[nt][r] = fmaf(hn, hn, pql[nt][r]);
        }
    }
    // reduce over the 16 ln15 lanes (channels); quad holds distinct p
    #pragma unroll
    for (int nt = 0; nt < 4; nt++)
        #pragma unroll
        for (int r = 0; r < 4; r++) {
            float s = psl[nt][r], q = pql[nt][r];
            s += __shfl_xor(s, 1, 64); q += __shfl_xor(q, 1, 64);
            s += __shfl_xor(s, 2, 64); q += __shfl_xor(q, 2, 64);
            s += __shfl_xor(s, 4, 64); q += __shfl_xor(q, 4, 64);
            s += __shfl_xor(s, 8, 64); q += __shfl_xor(q, 8, 64);
            psl[nt][r] = s; pql[nt][r] = q;
        }
    if (ln15 == 0) {
        #pragma unroll
        for (int nt = 0; nt < 4; nt++)
            #pragma unroll
            for (int r = 0; r < 4; r++) {
                int p = nt * 16 + quad * 4 + r;
                sred[w][p] = psl[nt][r];
                sqred[w][p] = pql[nt][r];
            }
    }
    __syncthreads();
    if (t < 64) {
        float S = 0.f, Q = 0.f;
        #pragma unroll
        for (int s_ = 0; s_ < 16; s_++) { S += sred[s_][t]; Q += sqred[s_][t]; }
        float mu = S * (1.f / 256.f);
        float var = Q * (1.f / 256.f) - mu * mu;
        mup[t] = mu; rstd[t] = rsqrtf(var + 1e-5f);
    }
    __syncthreads();

    {
        float gm = ln_g[li * 256 + o];
        float bt = ln_b[li * 256 + o];
        ushort_t* hw = hb_ + (size_t)o * 4096 + l0 + quad * 4;
        #pragma unroll
        for (int nt = 0; nt < 4; nt++) {
            us4 ov;
            ushort_t* op = &ov.x;
            #pragma unroll
            for (int r = 0; r < 4; r++) {
                int p = nt * 16 + quad * 4 + r;
                float v = (accA[nt][r] - mup[p]) * rstd[p] * gm + bt;
                op[r] = f2bf(v);
            }
            *(us4*)(hw + nt * 16) = ov;
        }
    }
}

// ---------------- decoder (bf16 h) ----------------
__global__ __launch_bounds__(256) void dec1_kernel(const ushort_t* __restrict__ Hb,
    const float* __restrict__ w1, const float* __restrict__ b1, float* __restrict__ y1)
{
    int bh = blockIdx.x;
    const ushort_t* base = Hb + (size_t)bh * 4096;
    int t = threadIdx.x;
    float s = 0.f;
    for (int l = t; l < 4096; l += 256) s = fmaf(bf2f(base[l]), w1[l], s);
    #pragma unroll
    for (int d = 32; d > 0; d >>= 1) s += __shfl_xor(s, d, 64);
    __shared__ float red[4];
    if ((t & 63) == 0) red[t >> 6] = s;
    __syncthreads();
    if (t == 0) y1[bh] = red[0] + red[1] + red[2] + red[3] + b1[0];
}

__global__ __launch_bounds__(256) void dec2_kernel(const float* __restrict__ y1,
    const float* __restrict__ w2, const float* __restrict__ b2, float* __restrict__ out)
{
    int t = threadIdx.x;
    int b = blockIdx.x * 4 + (t >> 6);
    int lane = t & 63;
    float s = 0.f;
    #pragma unroll
    for (int k = 0; k < 4; k++) s = fmaf(y1[b * 256 + lane + k * 64], w2[lane + k * 64], s);
    #pragma unroll
    for (int d = 32; d > 0; d >>= 1) s += __shfl_xor(s, d, 64);
    if (lane == 0) out[b] = 1.f / (1.f + expf(-(s + b2[0])));
}

extern "C" void kernel_launch(void* const* d_in, const int* in_sizes, int n_in,
                              void* d_out, int out_size, void* d_ws, size_t ws_size,
                              hipStream_t stream)
{
    const float* x      = (const float*)d_in[0];
    const float* enc_w  = (const float*)d_in[1];
    const float* enc_b  = (const float*)d_in[2];
    const float* log_dt = (const float*)d_in[3];
    const float* lAr    = (const float*)d_in[4];
    const float* Aim    = (const float*)d_in[5];
    const float* Cre    = (const float*)d_in[6];
    const float* Cim    = (const float*)d_in[7];
    const float* Dp     = (const float*)d_in[8];
    const float* glu_w  = (const float*)d_in[9];
    const float* glu_b  = (const float*)d_in[10];
    const float* ln_g   = (const float*)d_in[11];
    const float* ln_b   = (const float*)d_in[12];
    const float* w1     = (const float*)d_in[13];
    const float* b1     = (const float*)d_in[14];
    const float* w2     = (const float*)d_in[15];
    const float* b2     = (const float*)d_in[16];

    float* ws = (float*)d_ws;
    ushort_t* Hb   = (ushort_t*)ws;
    ushort_t* wTb  = (ushort_t*)(ws + WS_WT);
    float* y1      = ws + WS_Y1;
    float* a256    = ws + WS_A256;
    ushort_t* Vg   = (ushort_t*)(ws + WS_V);
    ushort_t* Abuf = (ushort_t*)(ws + WS_ABUF);
    float* outp    = (float*)d_out;

    size_t wsf = ws_size / 4;
    int nb = 32;
    while (nb > 4 && (size_t)WS_S + (size_t)nb * 655360 > wsf) nb >>= 1;
    ushort_t* Gb = (ushort_t*)(ws + WS_S + (size_t)nb * 131072);

    wtb_kernel<<<2048, 256, 0, stream>>>(glu_w, wTb);
    enc_kernel<<<16384, 256, 0, stream>>>(x, enc_w, enc_b, Hb);
    for (int li = 0; li < 4; li++) {
        prep_kernel<<<256, 256, 0, stream>>>(log_dt, lAr, Aim, Cre, Cim, Abuf, Vg, a256, li);
        for (int b0 = 0; b0 < 32; b0 += nb) {
            s4df_kernel<<<dim3(256, nb / 4), 256, 0, stream>>>(Hb, Abuf, Vg, a256, Dp, Gb, li, b0);
            gluln_kernel<<<nb * 64, 1024, 0, stream>>>(Gb, wTb, glu_b, ln_g, ln_b, Hb, li, b0);
        }
    }
    dec1_kernel<<<8192, 256, 0, stream>>>(Hb, w1, b1, y1);
    dec2_kernel<<<8, 256, 0, stream>>>(y1, w2, b2, outp);
}

// Round 17
// 1003.773 us; speedup vs baseline: 1.0938x; 1.0938x over previous
//
#include <hip/hip_runtime.h>
#include <math.h>

// Problem constants: B=32, L=4096, CH=1, H=256, NL=4, N2=32
// Residual stream Hbf is bf16 [b][h][l]. Chunked-linear S4D:
//   y = T_h u + W_h seed, S = V_h u, seeds via per-batch 16-chunk serial scan.
// R12 fused s4df; R14 coalesced prep; R17: sS eliminated (V-GEMM writes S into yt's
// seed columns; scan runs in place) -> LDS 40KB exact -> 4 blocks/CU. gluln FROZEN
// at R12 (R10 tile-shrink, R13 two-pass, R16 wave-split all regressed).
// ws layout (float units):
#define WS_WT   16777216   // wTb bf16 (NL,512,256): 262,144 f
#define WS_Y1   17039360   // y1 fp32: 8,192 f
#define WS_A256 17047552   // a256 fp32 [256h][32s][2]: 16,384 f
#define WS_V    17063936   // V bf16 [256h][64][256]: 2,097,152 f
#define WS_ABUF 19161088   // A=[T|W] bf16 [256h][256][320]: 10,485,760 f
#define WS_S    29646848   // (slot retained) then Gb
// high-water nb=32: 29,646,848 + 32*655,360 = 50,618,368 f = 202.5 MB

typedef unsigned short ushort_t;
struct __attribute__((aligned(8))) us4 { ushort_t x, y, z, w; };
typedef short bf16x8 __attribute__((ext_vector_type(8)));
typedef float f32x4  __attribute__((ext_vector_type(4)));

__device__ __forceinline__ float bf2f(ushort_t u) {
    union { unsigned int i; float f; } c; c.i = ((unsigned int)u) << 16; return c.f;
}
__device__ __forceinline__ ushort_t f2bf(float f) {
    union { float f; unsigned int i; } c; c.f = f;
    unsigned int x = c.i;
    unsigned int r = (x + 0x7FFF + ((x >> 16) & 1)) >> 16;   // RNE
    return (ushort_t)r;
}
// gelu via tanh-form sigmoid: max |err| vs exact erf-gelu ~7e-4, overflow-safe.
__device__ __forceinline__ float fast_gelu(float v) {
    float y = 1.5957691216057308f * (v + 0.044715f * v * v * v); // 2*sqrt(2/pi)
    return v / (1.f + __expf(-y));
}

// ---------------- encoder: bf16 h[b][h][l] ----------------
__global__ __launch_bounds__(256) void enc_kernel(const float* __restrict__ x,
    const float* __restrict__ ew, const float* __restrict__ eb, ushort_t* __restrict__ Hb)
{
    int i = blockIdx.x * 256 + threadIdx.x;      // 8-us units, 4,194,304 total
    int l8 = i & 511;
    int h  = (i >> 9) & 255;
    int b  = i >> 17;
    const float* xp = x + ((size_t)b << 12) + (l8 << 3);
    float4 a0 = ((const float4*)xp)[0];
    float4 a1 = ((const float4*)xp)[1];
    float w = ew[h], bb = eb[h];
    us4 o0, o1;
    o0.x = f2bf(fmaf(a0.x, w, bb)); o0.y = f2bf(fmaf(a0.y, w, bb));
    o0.z = f2bf(fmaf(a0.z, w, bb)); o0.w = f2bf(fmaf(a0.w, w, bb));
    o1.x = f2bf(fmaf(a1.x, w, bb)); o1.y = f2bf(fmaf(a1.y, w, bb));
    o1.z = f2bf(fmaf(a1.z, w, bb)); o1.w = f2bf(fmaf(a1.w, w, bb));
    us4* op = (us4*)(Hb + ((size_t)i << 3));
    op[0] = o0; op[1] = o1;
}

// ---------------- weight cast ----------------
__global__ __launch_bounds__(256) void wtb_kernel(const float* __restrict__ gw, ushort_t* __restrict__ wTb)
{
    int i = blockIdx.x * 256 + threadIdx.x;      // 524,288
    wTb[i] = f2bf(gw[i]);
}

// ---------------- prep: build A=[T|W], V, a256; coalesced Abuf writeout --------------
__global__ __launch_bounds__(256) void prep_kernel(
    const float* __restrict__ log_dt, const float* __restrict__ lAr,
    const float* __restrict__ Aim_, const float* __restrict__ Cre,
    const float* __restrict__ Cim, ushort_t* __restrict__ Abuf,
    ushort_t* __restrict__ Vg, float* __restrict__ a256tab, int li)
{
    __shared__ float s_ar[32], s_ai[32], s_ckr[32], s_cki[32];
    __shared__ float powr[8][32], powi[8][32];
    __shared__ ushort_t kb[256];
    __shared__ ushort_t Vt[256][66];
    __shared__ ushort_t Wt[256][66];
    int t = threadIdx.x;
    int h = blockIdx.x;
    int pb = (li * 256 + h) * 32;

    if (t < 32) {
        int s = t;
        float dt = expf(log_dt[li * 256 + h]);
        float Are = -expf(lAr[pb + s]);
        float Ai  = Aim_[pb + s];
        float e = expf(Are * dt);
        float ar = e * cosf(Ai * dt), ai = e * sinf(Ai * dt);
        float inv = 1.f / (Are * Are + Ai * Ai);
        float numr = ar - 1.f, numi = ai;
        float tr = (numr * Are + numi * Ai) * inv;
        float ti = (numi * Are - numr * Ai) * inv;
        float cr = Cre[pb + s], ci = Cim[pb + s];
        s_ar[s] = ar; s_ai[s] = ai;
        s_ckr[s] = 2.f * (cr * tr - ci * ti);
        s_cki[s] = 2.f * (cr * ti + ci * tr);
        float xr = ar, xi = ai;
        for (int k = 0; k < 8; k++) {
            powr[k][s] = xr; powi[k][s] = xi;
            float nr = xr * xr - xi * xi;
            float ni = 2.f * xr * xi;
            xr = nr; xi = ni;
        }
        a256tab[h * 64 + s * 2] = xr;
        a256tab[h * 64 + s * 2 + 1] = xi;
    }
    __syncthreads();

    int d = t;
    float adr[32], adi[32];
    #pragma unroll
    for (int s = 0; s < 32; s++) { adr[s] = 1.f; adi[s] = 0.f; }
    #pragma unroll
    for (int bit = 0; bit < 8; bit++) {
        if (d & (1 << bit)) {
            #pragma unroll
            for (int s = 0; s < 32; s++) {
                float pr_ = powr[bit][s], pi_ = powi[bit][s];
                float nr = adr[s] * pr_ - adi[s] * pi_;
                float ni = adr[s] * pi_ + adi[s] * pr_;
                adr[s] = nr; adi[s] = ni;
            }
        }
    }
    float kd = 0.f;
    #pragma unroll
    for (int s = 0; s < 32; s++) kd += s_ckr[s] * adr[s] - s_cki[s] * adi[s];
    kb[d] = f2bf(kd);
    #pragma unroll
    for (int s = 0; s < 32; s++) {                // W row d -> Wt (LDS)
        float wr = adr[s] * s_ar[s] - adi[s] * s_ai[s];
        float wi = adr[s] * s_ai[s] + adi[s] * s_ar[s];
        float v0 = s_ckr[s] * wr - s_cki[s] * wi;
        float v1 = -(s_ckr[s] * wi + s_cki[s] * wr);
        *(unsigned int*)&Wt[d][2 * s] =
            (unsigned int)f2bf(v0) | ((unsigned int)f2bf(v1) << 16);
    }
    {
        int e = 255 - d;
        float evr[32], evi[32];
        #pragma unroll
        for (int s = 0; s < 32; s++) { evr[s] = 1.f; evi[s] = 0.f; }
        #pragma unroll
        for (int bit = 0; bit < 8; bit++) {
            if (e & (1 << bit)) {
                #pragma unroll
                for (int s = 0; s < 32; s++) {
                    float pr_ = powr[bit][s], pi_ = powi[bit][s];
                    float nr = evr[s] * pr_ - evi[s] * pi_;
                    float ni = evr[s] * pi_ + evi[s] * pr_;
                    evr[s] = nr; evi[s] = ni;
                }
            }
        }
        #pragma unroll
        for (int s = 0; s < 32; s++) {
            Vt[d][2*s]   = f2bf(evr[s]);
            Vt[d][2*s+1] = f2bf(evi[s]);
        }
    }
    __syncthreads();

    // coalesced [T|W] writeout: thread t stores us4 f = i*256+t
    {
        ushort_t* Ab = Abuf + (size_t)h * 81920;
        #pragma unroll 4
        for (int i = 0; i < 80; i++) {
            int f = i * 256 + t;                  // 0..20479
            int row = f / 80;
            int cq = f - row * 80;
            int col = cq * 4;
            us4 v;
            if (col < 256) {
                int idx = row - col;
                v.x = (idx >= 0) ? kb[idx]     : (ushort_t)0;
                v.y = (idx >= 1) ? kb[idx - 1] : (ushort_t)0;
                v.z = (idx >= 2) ? kb[idx - 2] : (ushort_t)0;
                v.w = (idx >= 3) ? kb[idx - 3] : (ushort_t)0;
            } else {
                int wc = col - 256;
                v.x = Wt[row][wc]; v.y = Wt[row][wc + 1];
                v.z = Wt[row][wc + 2]; v.w = Wt[row][wc + 3];
            }
            *(us4*)(Ab + (size_t)f * 4) = v;
        }
    }
    // V out
    {
        int m = t >> 2, jq = t & 3;
        ushort_t* vrow = Vg + (size_t)h * 16384 + (size_t)m * 256 + jq * 64;
        for (int j4 = 0; j4 < 16; j4++) {
            int j = jq * 64 + j4 * 4;
            us4 v;
            v.x = Vt[j][m]; v.y = Vt[j+1][m]; v.z = Vt[j+2][m]; v.w = Vt[j+3][m];
            *(us4*)(vrow + j4 * 4) = v;
        }
    }
}

// ---------------- fused S4D: V-GEMM -> in-place LDS scan -> [T|W]-GEMM + gelu -> G ---
// R17: S written straight into yt's seed columns (col 256+m, same swizzle the main
// GEMM reads); scan reads-then-replaces in place. LDS = 40,960 B exactly -> 4
// blocks/CU. R15's reg-dbuf removed (measured neutral) to keep VGPR <= 128.
__global__ __launch_bounds__(256, 4) void s4df_kernel(
    const ushort_t* __restrict__ U, const ushort_t* __restrict__ Abuf,
    const ushort_t* __restrict__ Vg, const float* __restrict__ a256tab,
    const float* __restrict__ Dp, ushort_t* __restrict__ G, int li, int b0)
{
    __shared__ ushort_t yt[64 * 320];             // 40 KiB exact, chunk c' = c ^ (row&7)
    int t = threadIdx.x;
    int h = blockIdx.x;
    int tile = blockIdx.y;
    int nl = t & 63, kq = t >> 6;
    int n = tile * 64 + nl;
    int sw = nl & 7;
    const ushort_t* ub = U + (size_t)(b0 + (n >> 4)) * 1048576 + (size_t)h * 4096 + (n & 15) * 256;
    #pragma unroll
    for (int i = 0; i < 8; i++) {
        int c = kq * 8 + i;
        *(uint4*)(&yt[nl * 320 + ((c ^ sw) << 3)]) = *(const uint4*)(ub + c * 8);
    }
    __syncthreads();

    int lane = t & 63, w = t >> 6;
    int ln15 = lane & 15, quad = lane >> 4;
    int rsw = ln15 & 7;

    // --- V-GEMM: S = V_h . u, written straight into yt seed columns ---
    {
        const ushort_t* va = Vg + (size_t)h * 16384 + (size_t)(w * 16 + ln15) * 256;
        f32x4 acc[4] = {};
        for (int ks = 0; ks < 8; ks++) {
            int c = ks * 4 + quad;
            bf16x8 af = *(const bf16x8*)(va + ks * 32 + quad * 8);
            #pragma unroll
            for (int nt = 0; nt < 4; nt++) {
                bf16x8 bf_ = *(const bf16x8*)(&yt[(nt * 16 + ln15) * 320 + ((c ^ rsw) << 3)]);
                acc[nt] = __builtin_amdgcn_mfma_f32_16x16x32_bf16(af, bf_, acc[nt], 0, 0, 0);
            }
        }
        __syncthreads();                          // all B-reads of u done before seed writes
        #pragma unroll
        for (int nt = 0; nt < 4; nt++) {
            int nn = nt * 16 + ln15;
            int nsw = nn & 7;
            #pragma unroll
            for (int r = 0; r < 4; r++) {
                int col = 256 + w * 16 + quad * 4 + r;   // S row m -> col 256+m
                int cc = col >> 3, off = col & 7;
                yt[nn * 320 + ((cc ^ nsw) << 3) + off] = f2bf(acc[nt][r]);
            }
        }
    }
    __syncthreads();

    // --- per-batch serial scan (4 b x 32 states), in place in yt seed cols ---
    if (t < 128) {
        int bq = t >> 5, s = t & 31;
        float m2r = a256tab[h * 64 + s * 2], m2i = a256tab[h * 64 + s * 2 + 1];
        int colR = 256 + 2 * s;                   // Re col; Im at colR+1 (same 8-chunk)
        int cc = colR >> 3, offR = colR & 7;
        float sr = 0.f, si = 0.f;
        for (int c = 0; c < 16; c++) {
            int nn = bq * 16 + c;
            int base = nn * 320 + ((cc ^ (nn & 7)) << 3);
            float Sr = bf2f(yt[base + offR]);
            float Si = bf2f(yt[base + offR + 1]);
            yt[base + offR]     = f2bf(sr);
            yt[base + offR + 1] = f2bf(si);
            float nsr = m2r * sr - m2i * si + Sr;
            float nsi = m2r * si + m2i * sr + Si;
            sr = nsr; si = nsi;
        }
    }
    __syncthreads();

    // --- main GEMM: y = [T|W].[u;seed], + D*u, gelu -> G ---
    const ushort_t* Ah = Abuf + (size_t)h * 81920;
    f32x4 acc[4][4] = {};
    for (int ks = 0; ks < 10; ks++) {
        int kk = ks * 32 + quad * 8;
        int c = ks * 4 + quad;
        bf16x8 af[4];
        #pragma unroll
        for (int mt = 0; mt < 4; mt++)
            af[mt] = *(const bf16x8*)(Ah + (size_t)(w * 64 + mt * 16 + ln15) * 320 + kk);
        #pragma unroll
        for (int nt = 0; nt < 4; nt++) {
            bf16x8 bf_ = *(const bf16x8*)(&yt[(nt * 16 + ln15) * 320 + ((c ^ rsw) << 3)]);
            #pragma unroll
            for (int mt = 0; mt < 4; mt++)
                acc[mt][nt] = __builtin_amdgcn_mfma_f32_16x16x32_bf16(af[mt], bf_, acc[mt][nt], 0, 0, 0);
        }
    }
    float Dh = Dp[li * 256 + h];
    #pragma unroll
    for (int mt = 0; mt < 4; mt++) {
        #pragma unroll
        for (int nt = 0; nt < 4; nt++) {
            int nn = tile * 64 + nt * 16 + ln15;
            int lb = w * 64 + mt * 16 + quad * 4;
            int c = lb >> 3, co = lb & 7;
            us4 uv = *(const us4*)(&yt[(nt * 16 + ln15) * 320 + ((c ^ rsw) << 3) + co]);
            float uu[4] = {bf2f(uv.x), bf2f(uv.y), bf2f(uv.z), bf2f(uv.w)};
            us4 o;
            ushort_t* op = &o.x;
            #pragma unroll
            for (int rr = 0; rr < 4; rr++) {
                float v = acc[mt][nt][rr] + Dh * uu[rr];
                op[rr] = f2bf(fast_gelu(v));
            }
            ushort_t* gp = G + ((size_t)(nn >> 4) * 256 + h) * 4096 + (nn & 15) * 256 + lb;
            *(us4*)gp = o;
        }
    }
}

// ---------------- GLU + residual + LayerNorm fused (R12-exact; FROZEN) ---------------
// Design space mapped: R10 tile-shrink (lost weight amortization), R13 two-pass
// (spilled), R16 16-wave split (4x LDS B-read traffic). 128+128 unified regs @
// 2 waves/SIMD is the optimum for this shape.
#define LDK 268
__global__ __launch_bounds__(256, 2) void gluln_kernel(
    const ushort_t* __restrict__ G, const ushort_t* __restrict__ wTb,
    const float* __restrict__ glu_b, const float* __restrict__ ln_g,
    const float* __restrict__ ln_b, ushort_t* __restrict__ Hb, int li, int b0)
{
    __shared__ ushort_t yt[64 * LDK];             // 34,304 B
    __shared__ float sred[4][64], sqred[4][64];
    __shared__ float mup[64], rstd[64];
    int t = threadIdx.x;
    int pf = blockIdx.x * 64;
    int bloc = pf >> 12;
    int l0 = pf & 4095;
    int b = b0 + bloc;

    const ushort_t* gb = G + (size_t)bloc * 1048576 + l0;
    unsigned int* dst = (unsigned int*)&yt[0];
    #pragma unroll
    for (int i = 0; i < 4; i++) {
        int hp = ((i & 1) << 6) + (t >> 2);       // 0..127
        int pg = ((i >> 1) << 2) + (t & 3);       // 0..7
        int h0 = hp * 2;
        uint4 va = *(const uint4*)(gb + (size_t)h0 * 4096 + pg * 8);
        uint4 vb = *(const uint4*)(gb + (size_t)(h0 + 1) * 4096 + pg * 8);
        const ushort_t* ra = (const ushort_t*)&va;
        const ushort_t* rb = (const ushort_t*)&vb;
        #pragma unroll
        for (int j = 0; j < 8; j++) {
            unsigned int v = (unsigned int)ra[j] | ((unsigned int)rb[j] << 16);
            dst[(pg * 8 + j) * (LDK / 2) + hp] = v;
        }
    }
    __syncthreads();

    int lane = t & 63, w = t >> 6;
    int ln15 = lane & 15, quad = lane >> 4;
    int oA = w * 64;
    const ushort_t* wA = wTb + li * 131072;

    f32x4 accA[4][4] = {};                        // row=quad*4+r (p), col=ln15 (o)
    f32x4 accG[4][4] = {};

    for (int ks = 0; ks < 8; ks++) {
        int kk = ks * 32 + quad * 8;
        bf16x8 af[4], gf[4];
        #pragma unroll
        for (int mt = 0; mt < 4; mt++) {
            int oa = oA + mt * 16 + ln15;
            af[mt] = *(const bf16x8*)(wA + (size_t)oa * 256 + kk);
            gf[mt] = *(const bf16x8*)(wA + (size_t)(oa + 256) * 256 + kk);
        }
        bf16x8 bfr[4];
        #pragma unroll
        for (int nt = 0; nt < 4; nt++) {
            const us4* yp = (const us4*)&yt[(nt * 16 + ln15) * LDK + kk];
            us4 lo = yp[0], hi = yp[1];
            bf16x8 v;
            v[0] = (short)lo.x; v[1] = (short)lo.y; v[2] = (short)lo.z; v[3] = (short)lo.w;
            v[4] = (short)hi.x; v[5] = (short)hi.y; v[6] = (short)hi.z; v[7] = (short)hi.w;
            bfr[nt] = v;
        }
        #pragma unroll
        for (int mt = 0; mt < 4; mt++)
            #pragma unroll
            for (int nt = 0; nt < 4; nt++) {
                accA[mt][nt] = __builtin_amdgcn_mfma_f32_16x16x32_bf16(bfr[nt], af[mt], accA[mt][nt], 0, 0, 0);
                accG[mt][nt] = __builtin_amdgcn_mfma_f32_16x16x32_bf16(bfr[nt], gf[mt], accG[mt][nt], 0, 0, 0);
            }
    }

    // prefetch H-old
    ushort_t* hb_ = Hb + (size_t)b * 1048576;
    us4 hold[4][4];
    #pragma unroll
    for (int mt = 0; mt < 4; mt++) {
        const ushort_t* hrow = hb_ + (size_t)(oA + mt * 16 + ln15) * 4096 + l0 + quad * 4;
        #pragma unroll
        for (int nt = 0; nt < 4; nt++)
            hold[mt][nt] = *(const us4*)(hrow + nt * 16);
    }

    float ba[4], bg[4];
    #pragma unroll
    for (int mt = 0; mt < 4; mt++) {
        int o = oA + mt * 16 + ln15;
        ba[mt] = glu_b[li * 512 + o];
        bg[mt] = glu_b[li * 512 + 256 + o];
    }

    float psl[4][4] = {}, pql[4][4] = {};
    #pragma unroll
    for (int mt = 0; mt < 4; mt++) {
        #pragma unroll
        for (int nt = 0; nt < 4; nt++) {
            const ushort_t* hp4 = &hold[mt][nt].x;
            #pragma unroll
            for (int r = 0; r < 4; r++) {
                float a = accA[mt][nt][r] + ba[mt];
                float g = accG[mt][nt][r] + bg[mt];
                float z = a / (1.f + __expf(-g));
                float hn = z + bf2f(hp4[r]);
                accA[mt][nt][r] = hn;
                psl[nt][r] += hn; pql[nt][r] = fmaf(hn, hn, pql[nt][r]);
            }
        }
    }
    #pragma unroll
    for (int nt = 0; nt < 4; nt++)
        #pragma unroll
        for (int r = 0; r < 4; r++) {
            float s = psl[nt][r], q = pql[nt][r];
            s += __shfl_xor(s, 1, 64); q += __shfl_xor(q, 1, 64);
            s += __shfl_xor(s, 2, 64); q += __shfl_xor(q, 2, 64);
            s += __shfl_xor(s, 4, 64); q += __shfl_xor(q, 4, 64);
            s += __shfl_xor(s, 8, 64); q += __shfl_xor(q, 8, 64);
            psl[nt][r] = s; pql[nt][r] = q;
        }
    if (ln15 == 0) {
        #pragma unroll
        for (int nt = 0; nt < 4; nt++)
            #pragma unroll
            for (int r = 0; r < 4; r++) {
                int p = nt * 16 + quad * 4 + r;
                sred[w][p] = psl[nt][r];
                sqred[w][p] = pql[nt][r];
            }
    }
    __syncthreads();
    if (t < 64) {
        float S = (sred[0][t] + sred[1][t]) + (sred[2][t] + sred[3][t]);
        float Q = (sqred[0][t] + sqred[1][t]) + (sqred[2][t] + sqred[3][t]);
        float mu = S * (1.f / 256.f);
        float var = Q * (1.f / 256.f) - mu * mu;
        mup[t] = mu; rstd[t] = rsqrtf(var + 1e-5f);
    }
    __syncthreads();

    #pragma unroll
    for (int mt = 0; mt < 4; mt++) {
        int o = oA + mt * 16 + ln15;
        float gm = ln_g[li * 256 + o];
        float bt = ln_b[li * 256 + o];
        ushort_t* hrow = hb_ + (size_t)o * 4096 + l0 + quad * 4;
        #pragma unroll
        for (int nt = 0; nt < 4; nt++) {
            us4 ov;
            ushort_t* op = &ov.x;
            #pragma unroll
            for (int r = 0; r < 4; r++) {
                int p = nt * 16 + quad * 4 + r;
                float v = (accA[mt][nt][r] - mup[p]) * rstd[p] * gm + bt;
                op[r] = f2bf(v);
            }
            *(us4*)(hrow + nt * 16) = ov;
        }
    }
}

// ---------------- decoder (bf16 h) ----------------
__global__ __launch_bounds__(256) void dec1_kernel(const ushort_t* __restrict__ Hb,
    const float* __restrict__ w1, const float* __restrict__ b1, float* __restrict__ y1)
{
    int bh = blockIdx.x;
    const ushort_t* base = Hb + (size_t)bh * 4096;
    int t = threadIdx.x;
    float s = 0.f;
    for (int l = t; l < 4096; l += 256) s = fmaf(bf2f(base[l]), w1[l], s);
    #pragma unroll
    for (int d = 32; d > 0; d >>= 1) s += __shfl_xor(s, d, 64);
    __shared__ float red[4];
    if ((t & 63) == 0) red[t >> 6] = s;
    __syncthreads();
    if (t == 0) y1[bh] = red[0] + red[1] + red[2] + red[3] + b1[0];
}

__global__ __launch_bounds__(256) void dec2_kernel(const float* __restrict__ y1,
    const float* __restrict__ w2, const float* __restrict__ b2, float* __restrict__ out)
{
    int t = threadIdx.x;
    int b = blockIdx.x * 4 + (t >> 6);
    int lane = t & 63;
    float s = 0.f;
    #pragma unroll
    for (int k = 0; k < 4; k++) s = fmaf(y1[b * 256 + lane + k * 64], w2[lane + k * 64], s);
    #pragma unroll
    for (int d = 32; d > 0; d >>= 1) s += __shfl_xor(s, d, 64);
    if (lane == 0) out[b] = 1.f / (1.f + expf(-(s + b2[0])));
}

extern "C" void kernel_launch(void* const* d_in, const int* in_sizes, int n_in,
                              void* d_out, int out_size, void* d_ws, size_t ws_size,
                              hipStream_t stream)
{
    const float* x      = (const float*)d_in[0];
    const float* enc_w  = (const float*)d_in[1];
    const float* enc_b  = (const float*)d_in[2];
    const float* log_dt = (const float*)d_in[3];
    const float* lAr    = (const float*)d_in[4];
    const float* Aim    = (const float*)d_in[5];
    const float* Cre    = (const float*)d_in[6];
    const float* Cim    = (const float*)d_in[7];
    const float* Dp     = (const float*)d_in[8];
    const float* glu_w  = (const float*)d_in[9];
    const float* glu_b  = (const float*)d_in[10];
    const float* ln_g   = (const float*)d_in[11];
    const float* ln_b   = (const float*)d_in[12];
    const float* w1     = (const float*)d_in[13];
    const float* b1     = (const float*)d_in[14];
    const float* w2     = (const float*)d_in[15];
    const float* b2     = (const float*)d_in[16];

    float* ws = (float*)d_ws;
    ushort_t* Hb   = (ushort_t*)ws;
    ushort_t* wTb  = (ushort_t*)(ws + WS_WT);
    float* y1      = ws + WS_Y1;
    float* a256    = ws + WS_A256;
    ushort_t* Vg   = (ushort_t*)(ws + WS_V);
    ushort_t* Abuf = (ushort_t*)(ws + WS_ABUF);
    float* outp    = (float*)d_out;

    size_t wsf = ws_size / 4;
    int nb = 32;
    while (nb > 4 && (size_t)WS_S + (size_t)nb * 655360 > wsf) nb >>= 1;
    ushort_t* Gb = (ushort_t*)(ws + WS_S + (size_t)nb * 131072);

    wtb_kernel<<<2048, 256, 0, stream>>>(glu_w, wTb);
    enc_kernel<<<16384, 256, 0, stream>>>(x, enc_w, enc_b, Hb);
    for (int li = 0; li < 4; li++) {
        prep_kernel<<<256, 256, 0, stream>>>(log_dt, lAr, Aim, Cre, Cim, Abuf, Vg, a256, li);
        for (int b0 = 0; b0 < 32; b0 += nb) {
            s4df_kernel<<<dim3(256, nb / 4), 256, 0, stream>>>(Hb, Abuf, Vg, a256, Dp, Gb, li, b0);
            gluln_kernel<<<nb * 64, 256, 0, stream>>>(Gb, wTb, glu_b, ln_g, ln_b, Hb, li, b0);
        }
    }
    dec1_kernel<<<8192, 256, 0, stream>>>(Hb, w1, b1, y1);
    dec2_kernel<<<8, 256, 0, stream>>>(y1, w2, b2, outp);
}

// Round 18
// 978.169 us; speedup vs baseline: 1.1225x; 1.0262x over previous
//
#include <hip/hip_runtime.h>
#include <math.h>

// Problem constants: B=32, L=4096, CH=1, H=256, NL=4, N2=32
// Residual stream Hbf is bf16 [b][h][l]. Chunked-linear S4D:
//   y = T_h u + W_h seed, S = V_h u, seeds via per-batch 16-chunk serial scan.
// R12 fused s4df; R14 coalesced prep; R17 in-place scan (LDS 40KB); R18: G-store
// coalesced via LDS bounce (was 2x write-amplified: 32B per 64B sector, cf. R11's
// WRITE_SIZE 119MB vs 64MB logical). gluln FROZEN at R12.
// ws layout (float units):
#define WS_WT   16777216   // wTb bf16 (NL,512,256): 262,144 f
#define WS_Y1   17039360   // y1 fp32: 8,192 f
#define WS_A256 17047552   // a256 fp32 [256h][32s][2]: 16,384 f
#define WS_V    17063936   // V bf16 [256h][64][256]: 2,097,152 f
#define WS_ABUF 19161088   // A=[T|W] bf16 [256h][256][320]: 10,485,760 f
#define WS_S    29646848   // (slot retained) then Gb
// high-water nb=32: 29,646,848 + 32*655,360 = 50,618,368 f = 202.5 MB

typedef unsigned short ushort_t;
struct __attribute__((aligned(8))) us4 { ushort_t x, y, z, w; };
typedef short bf16x8 __attribute__((ext_vector_type(8)));
typedef float f32x4  __attribute__((ext_vector_type(4)));

__device__ __forceinline__ float bf2f(ushort_t u) {
    union { unsigned int i; float f; } c; c.i = ((unsigned int)u) << 16; return c.f;
}
__device__ __forceinline__ ushort_t f2bf(float f) {
    union { float f; unsigned int i; } c; c.f = f;
    unsigned int x = c.i;
    unsigned int r = (x + 0x7FFF + ((x >> 16) & 1)) >> 16;   // RNE
    return (ushort_t)r;
}
// gelu via tanh-form sigmoid: max |err| vs exact erf-gelu ~7e-4, overflow-safe.
__device__ __forceinline__ float fast_gelu(float v) {
    float y = 1.5957691216057308f * (v + 0.044715f * v * v * v); // 2*sqrt(2/pi)
    return v / (1.f + __expf(-y));
}

// ---------------- encoder: bf16 h[b][h][l] ----------------
__global__ __launch_bounds__(256) void enc_kernel(const float* __restrict__ x,
    const float* __restrict__ ew, const float* __restrict__ eb, ushort_t* __restrict__ Hb)
{
    int i = blockIdx.x * 256 + threadIdx.x;      // 8-us units, 4,194,304 total
    int l8 = i & 511;
    int h  = (i >> 9) & 255;
    int b  = i >> 17;
    const float* xp = x + ((size_t)b << 12) + (l8 << 3);
    float4 a0 = ((const float4*)xp)[0];
    float4 a1 = ((const float4*)xp)[1];
    float w = ew[h], bb = eb[h];
    us4 o0, o1;
    o0.x = f2bf(fmaf(a0.x, w, bb)); o0.y = f2bf(fmaf(a0.y, w, bb));
    o0.z = f2bf(fmaf(a0.z, w, bb)); o0.w = f2bf(fmaf(a0.w, w, bb));
    o1.x = f2bf(fmaf(a1.x, w, bb)); o1.y = f2bf(fmaf(a1.y, w, bb));
    o1.z = f2bf(fmaf(a1.z, w, bb)); o1.w = f2bf(fmaf(a1.w, w, bb));
    us4* op = (us4*)(Hb + ((size_t)i << 3));
    op[0] = o0; op[1] = o1;
}

// ---------------- weight cast ----------------
__global__ __launch_bounds__(256) void wtb_kernel(const float* __restrict__ gw, ushort_t* __restrict__ wTb)
{
    int i = blockIdx.x * 256 + threadIdx.x;      // 524,288
    wTb[i] = f2bf(gw[i]);
}

// ---------------- prep: build A=[T|W], V, a256; coalesced Abuf writeout --------------
__global__ __launch_bounds__(256) void prep_kernel(
    const float* __restrict__ log_dt, const float* __restrict__ lAr,
    const float* __restrict__ Aim_, const float* __restrict__ Cre,
    const float* __restrict__ Cim, ushort_t* __restrict__ Abuf,
    ushort_t* __restrict__ Vg, float* __restrict__ a256tab, int li)
{
    __shared__ float s_ar[32], s_ai[32], s_ckr[32], s_cki[32];
    __shared__ float powr[8][32], powi[8][32];
    __shared__ ushort_t kb[256];
    __shared__ ushort_t Vt[256][66];
    __shared__ ushort_t Wt[256][66];
    int t = threadIdx.x;
    int h = blockIdx.x;
    int pb = (li * 256 + h) * 32;

    if (t < 32) {
        int s = t;
        float dt = expf(log_dt[li * 256 + h]);
        float Are = -expf(lAr[pb + s]);
        float Ai  = Aim_[pb + s];
        float e = expf(Are * dt);
        float ar = e * cosf(Ai * dt), ai = e * sinf(Ai * dt);
        float inv = 1.f / (Are * Are + Ai * Ai);
        float numr = ar - 1.f, numi = ai;
        float tr = (numr * Are + numi * Ai) * inv;
        float ti = (numi * Are - numr * Ai) * inv;
        float cr = Cre[pb + s], ci = Cim[pb + s];
        s_ar[s] = ar; s_ai[s] = ai;
        s_ckr[s] = 2.f * (cr * tr - ci * ti);
        s_cki[s] = 2.f * (cr * ti + ci * tr);
        float xr = ar, xi = ai;
        for (int k = 0; k < 8; k++) {
            powr[k][s] = xr; powi[k][s] = xi;
            float nr = xr * xr - xi * xi;
            float ni = 2.f * xr * xi;
            xr = nr; xi = ni;
        }
        a256tab[h * 64 + s * 2] = xr;
        a256tab[h * 64 + s * 2 + 1] = xi;
    }
    __syncthreads();

    int d = t;
    float adr[32], adi[32];
    #pragma unroll
    for (int s = 0; s < 32; s++) { adr[s] = 1.f; adi[s] = 0.f; }
    #pragma unroll
    for (int bit = 0; bit < 8; bit++) {
        if (d & (1 << bit)) {
            #pragma unroll
            for (int s = 0; s < 32; s++) {
                float pr_ = powr[bit][s], pi_ = powi[bit][s];
                float nr = adr[s] * pr_ - adi[s] * pi_;
                float ni = adr[s] * pi_ + adi[s] * pr_;
                adr[s] = nr; adi[s] = ni;
            }
        }
    }
    float kd = 0.f;
    #pragma unroll
    for (int s = 0; s < 32; s++) kd += s_ckr[s] * adr[s] - s_cki[s] * adi[s];
    kb[d] = f2bf(kd);
    #pragma unroll
    for (int s = 0; s < 32; s++) {                // W row d -> Wt (LDS)
        float wr = adr[s] * s_ar[s] - adi[s] * s_ai[s];
        float wi = adr[s] * s_ai[s] + adi[s] * s_ar[s];
        float v0 = s_ckr[s] * wr - s_cki[s] * wi;
        float v1 = -(s_ckr[s] * wi + s_cki[s] * wr);
        *(unsigned int*)&Wt[d][2 * s] =
            (unsigned int)f2bf(v0) | ((unsigned int)f2bf(v1) << 16);
    }
    {
        int e = 255 - d;
        float evr[32], evi[32];
        #pragma unroll
        for (int s = 0; s < 32; s++) { evr[s] = 1.f; evi[s] = 0.f; }
        #pragma unroll
        for (int bit = 0; bit < 8; bit++) {
            if (e & (1 << bit)) {
                #pragma unroll
                for (int s = 0; s < 32; s++) {
                    float pr_ = powr[bit][s], pi_ = powi[bit][s];
                    float nr = evr[s] * pr_ - evi[s] * pi_;
                    float ni = evr[s] * pi_ + evi[s] * pr_;
                    evr[s] = nr; evi[s] = ni;
                }
            }
        }
        #pragma unroll
        for (int s = 0; s < 32; s++) {
            Vt[d][2*s]   = f2bf(evr[s]);
            Vt[d][2*s+1] = f2bf(evi[s]);
        }
    }
    __syncthreads();

    // coalesced [T|W] writeout: thread t stores us4 f = i*256+t
    {
        ushort_t* Ab = Abuf + (size_t)h * 81920;
        #pragma unroll 4
        for (int i = 0; i < 80; i++) {
            int f = i * 256 + t;                  // 0..20479
            int row = f / 80;
            int cq = f - row * 80;
            int col = cq * 4;
            us4 v;
            if (col < 256) {
                int idx = row - col;
                v.x = (idx >= 0) ? kb[idx]     : (ushort_t)0;
                v.y = (idx >= 1) ? kb[idx - 1] : (ushort_t)0;
                v.z = (idx >= 2) ? kb[idx - 2] : (ushort_t)0;
                v.w = (idx >= 3) ? kb[idx - 3] : (ushort_t)0;
            } else {
                int wc = col - 256;
                v.x = Wt[row][wc]; v.y = Wt[row][wc + 1];
                v.z = Wt[row][wc + 2]; v.w = Wt[row][wc + 3];
            }
            *(us4*)(Ab + (size_t)f * 4) = v;
        }
    }
    // V out
    {
        int m = t >> 2, jq = t & 3;
        ushort_t* vrow = Vg + (size_t)h * 16384 + (size_t)m * 256 + jq * 64;
        for (int j4 = 0; j4 < 16; j4++) {
            int j = jq * 64 + j4 * 4;
            us4 v;
            v.x = Vt[j][m]; v.y = Vt[j+1][m]; v.z = Vt[j+2][m]; v.w = Vt[j+3][m];
            *(us4*)(vrow + j4 * 4) = v;
        }
    }
}

// ---------------- fused S4D: V-GEMM -> in-place LDS scan -> [T|W]-GEMM + gelu -> G ---
// R18: after the main GEMM the gelu results bounce through yt (re-laid-out as
// [nn][lb], 256-us rows, same XOR swizzle) so the G write is 512B-contiguous per
// half-wave (full 64B sectors). launch_bounds(256,3): +32 packed regs, spill-safe.
__global__ __launch_bounds__(256, 3) void s4df_kernel(
    const ushort_t* __restrict__ U, const ushort_t* __restrict__ Abuf,
    const ushort_t* __restrict__ Vg, const float* __restrict__ a256tab,
    const float* __restrict__ Dp, ushort_t* __restrict__ G, int li, int b0)
{
    __shared__ ushort_t yt[64 * 320];             // 40 KiB, chunk c' = c ^ (row&7)
    int t = threadIdx.x;
    int h = blockIdx.x;
    int tile = blockIdx.y;
    int nl = t & 63, kq = t >> 6;
    int n = tile * 64 + nl;
    int sw = nl & 7;
    const ushort_t* ub = U + (size_t)(b0 + (n >> 4)) * 1048576 + (size_t)h * 4096 + (n & 15) * 256;
    #pragma unroll
    for (int i = 0; i < 8; i++) {
        int c = kq * 8 + i;
        *(uint4*)(&yt[nl * 320 + ((c ^ sw) << 3)]) = *(const uint4*)(ub + c * 8);
    }
    __syncthreads();

    int lane = t & 63, w = t >> 6;
    int ln15 = lane & 15, quad = lane >> 4;
    int rsw = ln15 & 7;

    // --- V-GEMM: S = V_h . u, written straight into yt seed columns ---
    {
        const ushort_t* va = Vg + (size_t)h * 16384 + (size_t)(w * 16 + ln15) * 256;
        f32x4 acc[4] = {};
        for (int ks = 0; ks < 8; ks++) {
            int c = ks * 4 + quad;
            bf16x8 af = *(const bf16x8*)(va + ks * 32 + quad * 8);
            #pragma unroll
            for (int nt = 0; nt < 4; nt++) {
                bf16x8 bf_ = *(const bf16x8*)(&yt[(nt * 16 + ln15) * 320 + ((c ^ rsw) << 3)]);
                acc[nt] = __builtin_amdgcn_mfma_f32_16x16x32_bf16(af, bf_, acc[nt], 0, 0, 0);
            }
        }
        __syncthreads();                          // all B-reads of u done before seed writes
        #pragma unroll
        for (int nt = 0; nt < 4; nt++) {
            int nn = nt * 16 + ln15;
            int nsw = nn & 7;
            #pragma unroll
            for (int r = 0; r < 4; r++) {
                int col = 256 + w * 16 + quad * 4 + r;   // S row m -> col 256+m
                int cc = col >> 3, off = col & 7;
                yt[nn * 320 + ((cc ^ nsw) << 3) + off] = f2bf(acc[nt][r]);
            }
        }
    }
    __syncthreads();

    // --- per-batch serial scan (4 b x 32 states), in place in yt seed cols ---
    if (t < 128) {
        int bq = t >> 5, s = t & 31;
        float m2r = a256tab[h * 64 + s * 2], m2i = a256tab[h * 64 + s * 2 + 1];
        int colR = 256 + 2 * s;                   // Re col; Im at colR+1 (same 8-chunk)
        int cc = colR >> 3, offR = colR & 7;
        float sr = 0.f, si = 0.f;
        for (int c = 0; c < 16; c++) {
            int nn = bq * 16 + c;
            int base = nn * 320 + ((cc ^ (nn & 7)) << 3);
            float Sr = bf2f(yt[base + offR]);
            float Si = bf2f(yt[base + offR + 1]);
            yt[base + offR]     = f2bf(sr);
            yt[base + offR + 1] = f2bf(si);
            float nsr = m2r * sr - m2i * si + Sr;
            float nsi = m2r * si + m2i * sr + Si;
            sr = nsr; si = nsi;
        }
    }
    __syncthreads();

    // --- main GEMM: y = [T|W].[u;seed], + D*u, gelu -> packed regs ---
    const ushort_t* Ah = Abuf + (size_t)h * 81920;
    f32x4 acc[4][4] = {};
    for (int ks = 0; ks < 10; ks++) {
        int kk = ks * 32 + quad * 8;
        int c = ks * 4 + quad;
        bf16x8 af[4];
        #pragma unroll
        for (int mt = 0; mt < 4; mt++)
            af[mt] = *(const bf16x8*)(Ah + (size_t)(w * 64 + mt * 16 + ln15) * 320 + kk);
        #pragma unroll
        for (int nt = 0; nt < 4; nt++) {
            bf16x8 bf_ = *(const bf16x8*)(&yt[(nt * 16 + ln15) * 320 + ((c ^ rsw) << 3)]);
            #pragma unroll
            for (int mt = 0; mt < 4; mt++)
                acc[mt][nt] = __builtin_amdgcn_mfma_f32_16x16x32_bf16(af[mt], bf_, acc[mt][nt], 0, 0, 0);
        }
    }
    float Dh = Dp[li * 256 + h];
    unsigned int pk[4][4][2];                     // packed bf16 pairs [mt][nt][r01|r23]
    #pragma unroll
    for (int mt = 0; mt < 4; mt++) {
        int lb = w * 64 + mt * 16 + quad * 4;
        int c = lb >> 3, co = lb & 7;
        #pragma unroll
        for (int nt = 0; nt < 4; nt++) {
            us4 uv = *(const us4*)(&yt[(nt * 16 + ln15) * 320 + ((c ^ rsw) << 3) + co]);
            float uu[4] = {bf2f(uv.x), bf2f(uv.y), bf2f(uv.z), bf2f(uv.w)};
            ushort_t g0 = f2bf(fast_gelu(acc[mt][nt][0] + Dh * uu[0]));
            ushort_t g1 = f2bf(fast_gelu(acc[mt][nt][1] + Dh * uu[1]));
            ushort_t g2 = f2bf(fast_gelu(acc[mt][nt][2] + Dh * uu[2]));
            ushort_t g3 = f2bf(fast_gelu(acc[mt][nt][3] + Dh * uu[3]));
            pk[mt][nt][0] = (unsigned int)g0 | ((unsigned int)g1 << 16);
            pk[mt][nt][1] = (unsigned int)g2 | ((unsigned int)g3 << 16);
        }
    }
    __syncthreads();                              // all u-reads done; yt reusable

    // scatter results into yt as [nn][lb] (256-us rows, low-3-bit XOR swizzle)
    #pragma unroll
    for (int mt = 0; mt < 4; mt++) {
        int lb0 = w * 64 + mt * 16 + quad * 4;
        int ch = lb0 >> 3, off = lb0 & 7;
        #pragma unroll
        for (int nt = 0; nt < 4; nt++) {
            int nn = nt * 16 + ln15;
            unsigned int* dp = (unsigned int*)&yt[nn * 256 + ((ch ^ (nn & 7)) << 3) + off];
            dp[0] = pk[mt][nt][0];
            dp[1] = pk[mt][nt][1];
        }
    }
    __syncthreads();

    // coalesced copy-out: half-wave = one 512B G row per instruction
    {
        int nn0 = t >> 5;                         // 0..7, +8 per iter
        int c2 = t & 31;                          // 16B chunk within row
        #pragma unroll
        for (int it = 0; it < 8; it++) {
            int nn = nn0 + it * 8;
            int nn_g = tile * 64 + nn;
            uint4 v = *(const uint4*)&yt[nn * 256 + ((c2 ^ (nn & 7)) << 3)];
            ushort_t* gp = G + ((size_t)(nn_g >> 4) * 256 + h) * 4096
                             + (size_t)(nn_g & 15) * 256 + c2 * 8;
            *(uint4*)gp = v;
        }
    }
}

// ---------------- GLU + residual + LayerNorm fused (R12-exact; FROZEN) ---------------
#define LDK 268
__global__ __launch_bounds__(256, 2) void gluln_kernel(
    const ushort_t* __restrict__ G, const ushort_t* __restrict__ wTb,
    const float* __restrict__ glu_b, const float* __restrict__ ln_g,
    const float* __restrict__ ln_b, ushort_t* __restrict__ Hb, int li, int b0)
{
    __shared__ ushort_t yt[64 * LDK];             // 34,304 B
    __shared__ float sred[4][64], sqred[4][64];
    __shared__ float mup[64], rstd[64];
    int t = threadIdx.x;
    int pf = blockIdx.x * 64;
    int bloc = pf >> 12;
    int l0 = pf & 4095;
    int b = b0 + bloc;

    const ushort_t* gb = G + (size_t)bloc * 1048576 + l0;
    unsigned int* dst = (unsigned int*)&yt[0];
    #pragma unroll
    for (int i = 0; i < 4; i++) {
        int hp = ((i & 1) << 6) + (t >> 2);       // 0..127
        int pg = ((i >> 1) << 2) + (t & 3);       // 0..7
        int h0 = hp * 2;
        uint4 va = *(const uint4*)(gb + (size_t)h0 * 4096 + pg * 8);
        uint4 vb = *(const uint4*)(gb + (size_t)(h0 + 1) * 4096 + pg * 8);
        const ushort_t* ra = (const ushort_t*)&va;
        const ushort_t* rb = (const ushort_t*)&vb;
        #pragma unroll
        for (int j = 0; j < 8; j++) {
            unsigned int v = (unsigned int)ra[j] | ((unsigned int)rb[j] << 16);
            dst[(pg * 8 + j) * (LDK / 2) + hp] = v;
        }
    }
    __syncthreads();

    int lane = t & 63, w = t >> 6;
    int ln15 = lane & 15, quad = lane >> 4;
    int oA = w * 64;
    const ushort_t* wA = wTb + li * 131072;

    f32x4 accA[4][4] = {};                        // row=quad*4+r (p), col=ln15 (o)
    f32x4 accG[4][4] = {};

    for (int ks = 0; ks < 8; ks++) {
        int kk = ks * 32 + quad * 8;
        bf16x8 af[4], gf[4];
        #pragma unroll
        for (int mt = 0; mt < 4; mt++) {
            int oa = oA + mt * 16 + ln15;
            af[mt] = *(const bf16x8*)(wA + (size_t)oa * 256 + kk);
            gf[mt] = *(const bf16x8*)(wA + (size_t)(oa + 256) * 256 + kk);
        }
        bf16x8 bfr[4];
        #pragma unroll
        for (int nt = 0; nt < 4; nt++) {
            const us4* yp = (const us4*)&yt[(nt * 16 + ln15) * LDK + kk];
            us4 lo = yp[0], hi = yp[1];
            bf16x8 v;
            v[0] = (short)lo.x; v[1] = (short)lo.y; v[2] = (short)lo.z; v[3] = (short)lo.w;
            v[4] = (short)hi.x; v[5] = (short)hi.y; v[6] = (short)hi.z; v[7] = (short)hi.w;
            bfr[nt] = v;
        }
        #pragma unroll
        for (int mt = 0; mt < 4; mt++)
            #pragma unroll
            for (int nt = 0; nt < 4; nt++) {
                accA[mt][nt] = __builtin_amdgcn_mfma_f32_16x16x32_bf16(bfr[nt], af[mt], accA[mt][nt], 0, 0, 0);
                accG[mt][nt] = __builtin_amdgcn_mfma_f32_16x16x32_bf16(bfr[nt], gf[mt], accG[mt][nt], 0, 0, 0);
            }
    }

    // prefetch H-old
    ushort_t* hb_ = Hb + (size_t)b * 1048576;
    us4 hold[4][4];
    #pragma unroll
    for (int mt = 0; mt < 4; mt++) {
        const ushort_t* hrow = hb_ + (size_t)(oA + mt * 16 + ln15) * 4096 + l0 + quad * 4;
        #pragma unroll
        for (int nt = 0; nt < 4; nt++)
            hold[mt][nt] = *(const us4*)(hrow + nt * 16);
    }

    float ba[4], bg[4];
    #pragma unroll
    for (int mt = 0; mt < 4; mt++) {
        int o = oA + mt * 16 + ln15;
        ba[mt] = glu_b[li * 512 + o];
        bg[mt] = glu_b[li * 512 + 256 + o];
    }

    float psl[4][4] = {}, pql[4][4] = {};
    #pragma unroll
    for (int mt = 0; mt < 4; mt++) {
        #pragma unroll
        for (int nt = 0; nt < 4; nt++) {
            const ushort_t* hp4 = &hold[mt][nt].x;
            #pragma unroll
            for (int r = 0; r < 4; r++) {
                float a = accA[mt][nt][r] + ba[mt];
                float g = accG[mt][nt][r] + bg[mt];
                float z = a / (1.f + __expf(-g));
                float hn = z + bf2f(hp4[r]);
                accA[mt][nt][r] = hn;
                psl[nt][r] += hn; pql[nt][r] = fmaf(hn, hn, pql[nt][r]);
            }
        }
    }
    #pragma unroll
    for (int nt = 0; nt < 4; nt++)
        #pragma unroll
        for (int r = 0; r < 4; r++) {
            float s = psl[nt][r], q = pql[nt][r];
            s += __shfl_xor(s, 1, 64); q += __shfl_xor(q, 1, 64);
            s += __shfl_xor(s, 2, 64); q += __shfl_xor(q, 2, 64);
            s += __shfl_xor(s, 4, 64); q += __shfl_xor(q, 4, 64);
            s += __shfl_xor(s, 8, 64); q += __shfl_xor(q, 8, 64);
            psl[nt][r] = s; pql[nt][r] = q;
        }
    if (ln15 == 0) {
        #pragma unroll
        for (int nt = 0; nt < 4; nt++)
            #pragma unroll
            for (int r = 0; r < 4; r++) {
                int p = nt * 16 + quad * 4 + r;
                sred[w][p] = psl[nt][r];
                sqred[w][p] = pql[nt][r];
            }
    }
    __syncthreads();
    if (t < 64) {
        float S = (sred[0][t] + sred[1][t]) + (sred[2][t] + sred[3][t]);
        float Q = (sqred[0][t] + sqred[1][t]) + (sqred[2][t] + sqred[3][t]);
        float mu = S * (1.f / 256.f);
        float var = Q * (1.f / 256.f) - mu * mu;
        mup[t] = mu; rstd[t] = rsqrtf(var + 1e-5f);
    }
    __syncthreads();

    #pragma unroll
    for (int mt = 0; mt < 4; mt++) {
        int o = oA + mt * 16 + ln15;
        float gm = ln_g[li * 256 + o];
        float bt = ln_b[li * 256 + o];
        ushort_t* hrow = hb_ + (size_t)o * 4096 + l0 + quad * 4;
        #pragma unroll
        for (int nt = 0; nt < 4; nt++) {
            us4 ov;
            ushort_t* op = &ov.x;
            #pragma unroll
            for (int r = 0; r < 4; r++) {
                int p = nt * 16 + quad * 4 + r;
                float v = (accA[mt][nt][r] - mup[p]) * rstd[p] * gm + bt;
                op[r] = f2bf(v);
            }
            *(us4*)(hrow + nt * 16) = ov;
        }
    }
}

// ---------------- decoder (bf16 h) ----------------
__global__ __launch_bounds__(256) void dec1_kernel(const ushort_t* __restrict__ Hb,
    const float* __restrict__ w1, const float* __restrict__ b1, float* __restrict__ y1)
{
    int bh = blockIdx.x;
    const ushort_t* base = Hb + (size_t)bh * 4096;
    int t = threadIdx.x;
    float s = 0.f;
    for (int l = t; l < 4096; l += 256) s = fmaf(bf2f(base[l]), w1[l], s);
    #pragma unroll
    for (int d = 32; d > 0; d >>= 1) s += __shfl_xor(s, d, 64);
    __shared__ float red[4];
    if ((t & 63) == 0) red[t >> 6] = s;
    __syncthreads();
    if (t == 0) y1[bh] = red[0] + red[1] + red[2] + red[3] + b1[0];
}

__global__ __launch_bounds__(256) void dec2_kernel(const float* __restrict__ y1,
    const float* __restrict__ w2, const float* __restrict__ b2, float* __restrict__ out)
{
    int t = threadIdx.x;
    int b = blockIdx.x * 4 + (t >> 6);
    int lane = t & 63;
    float s = 0.f;
    #pragma unroll
    for (int k = 0; k < 4; k++) s = fmaf(y1[b * 256 + lane + k * 64], w2[lane + k * 64], s);
    #pragma unroll
    for (int d = 32; d > 0; d >>= 1) s += __shfl_xor(s, d, 64);
    if (lane == 0) out[b] = 1.f / (1.f + expf(-(s + b2[0])));
}

extern "C" void kernel_launch(void* const* d_in, const int* in_sizes, int n_in,
                              void* d_out, int out_size, void* d_ws, size_t ws_size,
                              hipStream_t stream)
{
    const float* x      = (const float*)d_in[0];
    const float* enc_w  = (const float*)d_in[1];
    const float* enc_b  = (const float*)d_in[2];
    const float* log_dt = (const float*)d_in[3];
    const float* lAr    = (const float*)d_in[4];
    const float* Aim    = (const float*)d_in[5];
    const float* Cre    = (const float*)d_in[6];
    const float* Cim    = (const float*)d_in[7];
    const float* Dp     = (const float*)d_in[8];
    const float* glu_w  = (const float*)d_in[9];
    const float* glu_b  = (const float*)d_in[10];
    const float* ln_g   = (const float*)d_in[11];
    const float* ln_b   = (const float*)d_in[12];
    const float* w1     = (const float*)d_in[13];
    const float* b1     = (const float*)d_in[14];
    const float* w2     = (const float*)d_in[15];
    const float* b2     = (const float*)d_in[16];

    float* ws = (float*)d_ws;
    ushort_t* Hb   = (ushort_t*)ws;
    ushort_t* wTb  = (ushort_t*)(ws + WS_WT);
    float* y1      = ws + WS_Y1;
    float* a256    = ws + WS_A256;
    ushort_t* Vg   = (ushort_t*)(ws + WS_V);
    ushort_t* Abuf = (ushort_t*)(ws + WS_ABUF);
    float* outp    = (float*)d_out;

    size_t wsf = ws_size / 4;
    int nb = 32;
    while (nb > 4 && (size_t)WS_S + (size_t)nb * 655360 > wsf) nb >>= 1;
    ushort_t* Gb = (ushort_t*)(ws + WS_S + (size_t)nb * 131072);

    wtb_kernel<<<2048, 256, 0, stream>>>(glu_w, wTb);
    enc_kernel<<<16384, 256, 0, stream>>>(x, enc_w, enc_b, Hb);
    for (int li = 0; li < 4; li++) {
        prep_kernel<<<256, 256, 0, stream>>>(log_dt, lAr, Aim, Cre, Cim, Abuf, Vg, a256, li);
        for (int b0 = 0; b0 < 32; b0 += nb) {
            s4df_kernel<<<dim3(256, nb / 4), 256, 0, stream>>>(Hb, Abuf, Vg, a256, Dp, Gb, li, b0);
            gluln_kernel<<<nb * 64, 256, 0, stream>>>(Gb, wTb, glu_b, ln_g, ln_b, Hb, li, b0);
        }
    }
    dec1_kernel<<<8192, 256, 0, stream>>>(Hb, w1, b1, y1);
    dec2_kernel<<<8, 256, 0, stream>>>(y1, w2, b2, outp);
}